// Round 6
// baseline (686.594 us; speedup 1.0000x reference)
//
#include <hip/hip_runtime.h>

#define BB 16
#define NN 2048
#define MM 2048
#define EPSF 1e-9f

constexpr int CH  = 128;   // i-chunk length (col pass A)
constexpr int CHR = 128;   // l-chunk length (row pass A)

// Workspace layout:
//  P1[b*NN+i] = float4(x1, y1, z1, scale_i)   -- scale written by rowB
//  P2[b*MM+l] = float4(x2, y2, z2, remR_l)    -- remR updated by colB
//  remL[b*NN+i]
//  Pcol[b*MM+l] = remR_l * cons_l             -- written by colB
//  stS/stT[b*MM+l]   -- col partials (zeroed by init/colB)
//  stRS/stU[b*NN+i]  -- row partials (zeroed by init/rowB)

// ---------------- init ----------------
__global__ __launch_bounds__(256) void init_kernel(
    const float* __restrict__ xyz1, const float* __restrict__ xyz2,
    float4* __restrict__ P1, float4* __restrict__ P2,
    float* __restrict__ remL,
    float* __restrict__ stS, float* __restrict__ stT,
    float* __restrict__ stRS, float* __restrict__ stU,
    float* __restrict__ out)
{
    const int t = blockIdx.x * 256 + threadIdx.x;
    if (t < BB * NN) {
        P1[t] = make_float4(xyz1[3*t+0], xyz1[3*t+1], xyz1[3*t+2], 0.0f);
        remL[t] = 1.0f;
        stRS[t] = 0.0f; stU[t] = 0.0f;
    }
    if (t < BB * MM) {
        P2[t] = make_float4(xyz2[3*t+0], xyz2[3*t+1], xyz2[3*t+2], 1.0f); // .w = remR
        stS[t] = 0.0f; stT[t] = 0.0f;
    }
    if (t < BB) out[t] = 0.0f;
}

// ---------------- col pass A: partial s,t ----------------
// lane = column; stream of i is wave-uniform -> scalar loads. No LDS, no barrier.
__global__ __launch_bounds__(256) void colA(
    const float4* __restrict__ P1, const float4* __restrict__ P2,
    float* __restrict__ stS, float* __restrict__ stT, float coef)
{
    const int chunks = NN / CH;                   // 16
    const int bpbatch = (MM / 256) * chunks;      // 128
    const int batch = blockIdx.x / bpbatch;
    const int rem   = blockIdx.x % bpbatch;
    const int cg    = rem / chunks;               // 256-col group 0..7
    const int ic    = rem % chunks;               // i-chunk
    const int col   = cg * 256 + threadIdx.x;

    const float4 q = P2[batch * MM + col];
    const float qx = q.x, qy = q.y, qz = q.z;
    const float4* __restrict__ p1 = P1 + batch * NN + ic * CH;

    float s = 0.0f, t = 0.0f;
#pragma unroll 4
    for (int ii = 0; ii < CH; ++ii) {
        const float4 a = p1[ii];                  // wave-uniform -> s_load
        const float dx = a.x - qx, dy = a.y - qy, dz = a.z - qz;
        const float d2 = dx*dx + dy*dy + dz*dz;
        const float se = a.w * __builtin_amdgcn_exp2f(coef * d2);
        s += se;
        t = fmaf(se, __builtin_amdgcn_sqrtf(d2), t);
    }
    atomicAdd(&stS[batch * MM + col], s);
    atomicAdd(&stT[batch * MM + col], t);
}

// ---------------- col pass B: finalize cons/remR/Pcol/cost, reset st ----------------
__global__ __launch_bounds__(256) void colB(
    float4* __restrict__ P2, float* __restrict__ Pcol,
    float* __restrict__ stS, float* __restrict__ stT,
    float* __restrict__ out)
{
    const int idx = blockIdx.x * 256 + threadIdx.x;   // 0 .. BB*MM-1
    const int batch = idx / MM;                       // block-uniform
    float* p2w = (float*)P2;
    const float R = p2w[4 * idx + 3];
    const float s = stS[idx], t = stT[idx];
    stS[idx] = 0.0f; stT[idx] = 0.0f;
    const float sumr = s * R;
    const float cons = fminf(R / (sumr + EPSF), 1.0f);
    Pcol[idx] = R * cons;
    p2w[4 * idx + 3] = fmaxf(R - sumr * cons, 0.0f);
    float c = R * cons * t;
#pragma unroll
    for (int off = 32; off > 0; off >>= 1) c += __shfl_xor(c, off, 64);
    if ((threadIdx.x & 63) == 0) atomicAdd(out + batch, c);
}

// ---------------- row pass A: partial rs,u ----------------
// lane = row; stream of l is wave-uniform -> scalar loads. No LDS, no barrier.
// MODE 0: rs at coefNext only (first pass).
// MODE 1: u at level j via e_next^4, rs at level j+1 (coefNext).
// MODE 2: u at coefPrev direct, rs = sum(Rn) (level 0 => e_next = 1).
template<int MODE>
__global__ __launch_bounds__(256) void rowA(
    const float4* __restrict__ P2, const float* __restrict__ Pcol,
    const float4* __restrict__ P1,
    float* __restrict__ stRS, float* __restrict__ stU,
    float coefPrev, float coefNext)
{
    const int chunks = MM / CHR;                  // 16
    const int bpbatch = (NN / 256) * chunks;      // 128
    const int batch = blockIdx.x / bpbatch;
    const int rem   = blockIdx.x % bpbatch;
    const int rg    = rem / chunks;               // 256-row group 0..7
    const int ic    = rem % chunks;               // l-chunk
    const int row   = rg * 256 + threadIdx.x;

    const float4 p = P1[batch * NN + row];
    const float px = p.x, py = p.y, pz = p.z;
    const float4* __restrict__ p2 = P2 + batch * MM + ic * CHR;
    const float* __restrict__ pc  = Pcol + batch * MM + ic * CHR;

    float rs = 0.0f, u = 0.0f;
#pragma unroll 4
    for (int ii = 0; ii < CHR; ++ii) {
        const float4 q = p2[ii];                  // wave-uniform -> s_load
        const float dx = px - q.x, dy = py - q.y, dz = pz - q.z;
        const float d2 = dx*dx + dy*dy + dz*dz;
        if (MODE == 0) {
            rs = fmaf(__builtin_amdgcn_exp2f(coefNext * d2), q.w, rs);
        } else if (MODE == 1) {
            const float en = __builtin_amdgcn_exp2f(coefNext * d2);
            const float e2 = en * en;
            u  = fmaf(e2 * e2, pc[ii], u);        // e_prev = e_next^4
            rs = fmaf(en, q.w, rs);
        } else {
            const float ep = __builtin_amdgcn_exp2f(coefPrev * d2);
            u  = fmaf(ep, pc[ii], u);
            rs += q.w;                            // e_next = 1
        }
    }
    atomicAdd(&stRS[batch * NN + row], rs);
    if (MODE != 0) atomicAdd(&stU[batch * NN + row], u);
}

// ---------------- row pass B: finalize remL/scale, reset st ----------------
template<int MODE>
__global__ __launch_bounds__(256) void rowB(
    float4* __restrict__ P1, float* __restrict__ remL,
    float* __restrict__ stRS, float* __restrict__ stU)
{
    const int idx = blockIdx.x * 256 + threadIdx.x;   // 0 .. BB*NN-1
    float* p1w = (float*)P1;
    const float rs = stRS[idx];
    stRS[idx] = 0.0f;
    float L;
    if (MODE == 0) {
        L = remL[idx];                            // == 1
    } else {
        const float u = stU[idx];
        stU[idx] = 0.0f;
        L = fmaxf(remL[idx] - p1w[4 * idx + 3] * u, 0.0f);
        remL[idx] = L;
    }
    p1w[4 * idx + 3] = L / (rs + EPSF);           // scale
}

extern "C" void kernel_launch(void* const* d_in, const int* in_sizes, int n_in,
                              void* d_out, int out_size, void* d_ws, size_t ws_size,
                              hipStream_t stream)
{
    const float* xyz1 = (const float*)d_in[0];
    const float* xyz2 = (const float*)d_in[1];
    float* out = (float*)d_out;

    const int BN = BB * NN, BM = BB * MM;
    float4* P1 = (float4*)d_ws;
    float4* P2 = P1 + BN;
    float*  remL = (float*)(P2 + BM);
    float*  Pcol = remL + BN;
    float*  stS  = Pcol + BM;
    float*  stT  = stS + BM;
    float*  stRS = stT + BM;
    float*  stU  = stRS + BN;

    init_kernel<<<dim3((BN + 255) / 256), dim3(256), 0, stream>>>(
        xyz1, xyz2, P1, P2, remL, stS, stT, stRS, stU, out);

    // levels: j = 7..-1 -> -(4^j), then 0.  coef = level * log2(e)
    float coef[10];
    const double lv[10] = {-16384.0, -4096.0, -1024.0, -256.0, -64.0,
                           -16.0, -4.0, -1.0, -0.25, 0.0};
    for (int i = 0; i < 10; ++i) coef[i] = (float)(lv[i] * 1.4426950408889634);

    dim3 agrid(BB * (MM / 256) * (NN / CH));         // 2048
    dim3 rgrid(BB * (NN / 256) * (MM / CHR));        // 2048
    dim3 fgrid((BB * MM) / 256);                     // 128
    dim3 blk(256);

    rowA<0><<<rgrid, blk, 0, stream>>>(P2, Pcol, P1, stRS, stU, 0.0f, coef[0]);
    rowB<0><<<fgrid, blk, 0, stream>>>(P1, remL, stRS, stU);
    for (int j = 0; j < 10; ++j) {
        colA<<<agrid, blk, 0, stream>>>(P1, P2, stS, stT, coef[j]);
        colB<<<fgrid, blk, 0, stream>>>(P2, Pcol, stS, stT, out);
        if (j < 8) {
            rowA<1><<<rgrid, blk, 0, stream>>>(P2, Pcol, P1, stRS, stU, coef[j], coef[j+1]);
            rowB<1><<<fgrid, blk, 0, stream>>>(P1, remL, stRS, stU);
        } else if (j == 8) {
            rowA<2><<<rgrid, blk, 0, stream>>>(P2, Pcol, P1, stRS, stU, coef[8], 0.0f);
            rowB<1><<<fgrid, blk, 0, stream>>>(P1, remL, stRS, stU);
        }
    }
}